// Round 4
// baseline (477.228 us; speedup 1.0000x reference)
//
#include <hip/hip_runtime.h>

#define DIM 4096
#define NH 32
#define NKV 8
#define HD 128
#define WINDOW 1024
#define SEQ 2048
#define QLD 6144  // fused QKV row stride (u16 elems)

typedef unsigned int uint32;
typedef __attribute__((ext_vector_type(8))) short short8_t;
typedef __attribute__((ext_vector_type(8))) __bf16 bf16x8_t;
typedef __attribute__((ext_vector_type(4))) float floatx4_t;

__device__ __forceinline__ uint32 f2bf_bits(float f) {
  uint32 u = __builtin_bit_cast(uint32, f);
  return (u + 0x7fffu + ((u >> 16) & 1u)) >> 16;
}
__device__ __forceinline__ float bf2f(unsigned short b) {
  return __builtin_bit_cast(float, ((uint32)b) << 16);
}

template <class X, class Y> struct same_t { static constexpr bool v = false; };
template <class X> struct same_t<X, X> { static constexpr bool v = true; };

__device__ __forceinline__ void load_lds16(const unsigned short* g, unsigned short* l) {
  __builtin_amdgcn_global_load_lds((__attribute__((address_space(1))) void*)g,
                                   (__attribute__((address_space(3))) void*)l, 16, 0, 0);
}

// ============================================================================
// Counted-vmcnt pipelined bf16 GEMM (T3/T4): C[M,N] = A[M,K]*B[N,K]^T.
// BK=32, 3 LDS buffers (prefetch depth 2 tiles), raw s_barrier (no implicit
// vmcnt(0) drain), explicit counted s_waitcnt vmcnt(2*IT) in steady state.
// 8 waves (2M x 4N), 512 threads, 84KB LDS -> forced 1 block/CU; grids sized
// to exactly 256 blocks (full fill, no residency quantization).
// Rotate swizzle: LDS row r slot s holds K-chunk c=(s-(r>>1))&3 (8 elems),
// applied by pre-swizzling the per-lane global source (linear LDS dest,
// required by global_load_lds); ds_read_b128 frag reads hit each 16B bank
// position exactly 8x = conflict-free minimum.
// Race-freedom: stage(t+2) targets the buffer whose tile t-1 reads finished
// before the PREVIOUS iteration's post-read barrier; tile-t validity at read
// time = own vmcnt retires tile-t issues (oldest 4/3 of <=12/9 outstanding)
// + barrier makes all waves' loads visible. Every hazard pair is separated
// by an asm-"memory" fence, independent of s_barrier's memory modeling.
// ROPE=true: rotary fused into epilogue for cols < rope_ncols.
// ============================================================================
template <typename TC, bool ROPE, int BM, int BN>
__global__ __launch_bounds__(512, 2) void gemm_pipe(const unsigned short* __restrict__ A,
                                                    const unsigned short* __restrict__ B,
                                                    TC* __restrict__ C, int N, int K,
                                                    const float* __restrict__ cosp,
                                                    const float* __restrict__ sinp,
                                                    int rope_ncols) {
  constexpr int BK = 32;
  constexpr int MI = BM / 32;            // A frags per wave ((BM/2)/16)
  constexpr int NJ = BN / 64;            // B frags per wave ((BN/4)/16)
  constexpr int IA = (BM * 64) / 8192;   // A issues per tile (BM*BK*2B / 8KB)
  constexpr int IT = IA + 2;             // total issues per tile per thread
  constexpr int AE = BM * BK;            // A elems per buffer
  constexpr int BUFE = 14336;            // buffer stride elems (28672 B; x3 = 84KB)
  __shared__ unsigned short lds[3 * BUFE];

  const int tid = threadIdx.x;
  const int w = tid >> 6, lane = tid & 63;
  const int quad = lane >> 4, l16 = lane & 15;
  const int wm = w >> 2, wn = w & 3;
  const size_t m0 = (size_t)blockIdx.y * BM, n0 = (size_t)blockIdx.x * BN;

  // --- staging sources (per-lane, pre-swizzled). Each issue = 128 rows x 64B,
  //     thread t covers row (t>>2), slot (t&3); source chunk c=(slot-(row>>1))&3.
  const unsigned short* asrc[IA];
  const unsigned short* bsrc[2];
#pragma unroll
  for (int ii = 0; ii < IA; ii++) {
    const int rloc = ii * 128 + (tid >> 2);
    const int c = ((tid & 3) + 4 - ((rloc >> 1) & 3)) & 3;
    asrc[ii] = A + (m0 + rloc) * (size_t)K + c * 8;
  }
#pragma unroll
  for (int ii = 0; ii < 2; ii++) {
    // B tile BN rows: issue0 rows 0-127, issue1 rows BN-128..BN-1
    // (BN=192: rows 64-127 staged twice with identical data -> benign)
    const int r0 = ii ? (BN - 128) : 0;
    const int rloc = r0 + (tid >> 2);
    const int c = ((tid & 3) + 4 - ((rloc >> 1) & 3)) & 3;
    bsrc[ii] = B + (n0 + rloc) * (size_t)K + c * 8;
  }
  const int bdst1 = AE + (BN - 128) * BK;  // LDS elems offset of B issue1

  // --- fragment read offsets (static after unroll -> registers) ---
  int aoff[MI], boff[NJ];
#pragma unroll
  for (int i = 0; i < MI; i++) {
    const int row = wm * (BM / 2) + i * 16 + l16;
    const int s = (quad + (row >> 1)) & 3;
    aoff[i] = row * BK + s * 8;
  }
#pragma unroll
  for (int j = 0; j < NJ; j++) {
    const int row = wn * (BN / 4) + j * 16 + l16;
    const int s = (quad + (row >> 1)) & 3;
    boff[j] = AE + row * BK + s * 8;
  }

  auto stage = [&](int kt, int bi) {
    unsigned short* buf = lds + bi * BUFE + w * 512;  // wave-uniform dest base
    const size_t ko = (size_t)kt * BK;
#pragma unroll
    for (int ii = 0; ii < IA; ii++)
      load_lds16(asrc[ii] + ko, buf + ii * 4096);
    load_lds16(bsrc[0] + ko, buf + AE);
    load_lds16(bsrc[1] + ko, buf + bdst1);
  };

  floatx4_t acc[MI][NJ] = {};
  const int nt = K >> 5;  // 128

  stage(0, 0);
  stage(1, 1);
  int rb = 0;  // buffer holding tile t
  for (int t = 0; t < nt; t++) {
    int sb = rb + 2; if (sb >= 3) sb -= 3;
    if (t + 2 < nt) {
      stage(t + 2, sb);
      if constexpr (IT == 4) asm volatile("s_waitcnt vmcnt(8)" ::: "memory");
      else                   asm volatile("s_waitcnt vmcnt(6)" ::: "memory");
    } else if (t + 2 == nt) {
      if constexpr (IT == 4) asm volatile("s_waitcnt vmcnt(4)" ::: "memory");
      else                   asm volatile("s_waitcnt vmcnt(3)" ::: "memory");
    } else {
      asm volatile("s_waitcnt vmcnt(0)" ::: "memory");
    }
    __builtin_amdgcn_s_barrier();  // tile t visible to all waves
    const unsigned short* buf = lds + rb * BUFE;
    bf16x8_t afr[MI], bfr[NJ];
#pragma unroll
    for (int i = 0; i < MI; i++)
      afr[i] = __builtin_bit_cast(bf16x8_t, *(const short8_t*)(buf + aoff[i]));
#pragma unroll
    for (int j = 0; j < NJ; j++)
      bfr[j] = __builtin_bit_cast(bf16x8_t, *(const short8_t*)(buf + boff[j]));
    asm volatile("s_waitcnt lgkmcnt(0)" ::: "memory");  // reads done (fence)
    __builtin_amdgcn_s_barrier();  // buf[rb] free for tile t+3 next iter
    __builtin_amdgcn_s_setprio(1);
#pragma unroll
    for (int i = 0; i < MI; i++)
#pragma unroll
      for (int j = 0; j < NJ; j++)
        acc[i][j] = __builtin_amdgcn_mfma_f32_16x16x32_bf16(afr[i], bfr[j], acc[i][j], 0, 0, 0);
    __builtin_amdgcn_s_setprio(0);
    rb = (rb == 2) ? 0 : rb + 1;
  }

  // --- epilogue (+ optional fused RoPE) ---
#pragma unroll
  for (int i = 0; i < MI; i++)
#pragma unroll
    for (int j = 0; j < NJ; j++) {
      const int colb = (int)n0 + wn * (BN / 4) + j * 16;  // wave-uniform
      const bool do_rope = ROPE && (colb < rope_ncols);
#pragma unroll
      for (int r = 0; r < 4; r++) {
        size_t row = m0 + wm * (BM / 2) + i * 16 + quad * 4 + r;
        size_t col = n0 + wn * (BN / 4) + j * 16 + l16;
        float v = acc[i][j][r];
        if constexpr (ROPE) {
          if (do_rope) {  // 16-col tile never straddles rope_ncols (mult of 16)
            float pv = __shfl_xor(v, 1);
            const int d = ((int)col & 127) >> 1;
            const float c = cosp[row * 64 + d];
            const float s = sinp[row * 64 + d];
            v = ((int)col & 1) ? (pv * s + v * c) : (v * c - pv * s);
          }
        }
        if constexpr (same_t<TC, float>::v)
          C[row * (size_t)N + col] = v;
        else
          C[row * (size_t)N + col] = (unsigned short)f2bf_bits(v);
      }
    }
}

// Merged fp32->bf16 convert for {x, wq, wk, wv}: region-dispatched by block.
__global__ __launch_bounds__(256) void cvt4_kernel(const float* __restrict__ s0,
                                                   const float* __restrict__ s1,
                                                   const float* __restrict__ s2,
                                                   const float* __restrict__ s3,
                                                   unsigned short* __restrict__ d0,
                                                   unsigned short* __restrict__ d1,
                                                   unsigned short* __restrict__ d2,
                                                   unsigned short* __restrict__ d3) {
  const int b = blockIdx.x;
  const float* src;
  unsigned short* dst;
  int rb;
  if (b < 4096)        { src = s0; dst = d0; rb = b; }
  else if (b < 12288)  { src = s1; dst = d1; rb = b - 4096; }
  else if (b < 14336)  { src = s2; dst = d2; rb = b - 12288; }
  else                 { src = s3; dst = d3; rb = b - 14336; }
  const int idx = rb * 256 + threadIdx.x;
  const float4* p = (const float4*)src + (size_t)idx * 2;
  float4 a = p[0], bb = p[1];
  uint32 w0 = f2bf_bits(a.x) | (f2bf_bits(a.y) << 16);
  uint32 w1 = f2bf_bits(a.z) | (f2bf_bits(a.w) << 16);
  uint32 w2 = f2bf_bits(bb.x) | (f2bf_bits(bb.y) << 16);
  uint32 w3 = f2bf_bits(bb.z) | (f2bf_bits(bb.w) << 16);
  ((uint4*)dst)[idx] = make_uint4(w0, w1, w2, w3);
}

// Merged post-QKV-GEMM launch: blocks [0,8192) convert wo fp32->bf16 into wob;
// blocks [8192,8704) transpose v (qkvb col 5120, ld QLD) into vT[r][s].
__global__ __launch_bounds__(256) void epi_kernel(const float* __restrict__ wo,
                                                  unsigned short* __restrict__ wob,
                                                  const unsigned short* __restrict__ v,
                                                  unsigned short* __restrict__ vT) {
  __shared__ unsigned short t[64][72];
  const int b = blockIdx.x;
  const int tid = threadIdx.x;
  if (b < 8192) {
    const int idx = b * 256 + tid;
    const float4* p = (const float4*)wo + (size_t)idx * 2;
    float4 a = p[0], bb = p[1];
    uint32 w0 = f2bf_bits(a.x) | (f2bf_bits(a.y) << 16);
    uint32 w1 = f2bf_bits(a.z) | (f2bf_bits(a.w) << 16);
    uint32 w2 = f2bf_bits(bb.x) | (f2bf_bits(bb.y) << 16);
    uint32 w3 = f2bf_bits(bb.z) | (f2bf_bits(bb.w) << 16);
    ((uint4*)wob)[idx] = make_uint4(w0, w1, w2, w3);
    return;
  }
  const int bx = b - 8192;
  const int r0 = (bx & 15) * 64, s0 = (bx >> 4) * 64;
#pragma unroll
  for (int it = 0; it < 2; it++) {
    int f = it * 256 + tid;
    int si = f >> 3, cj = (f & 7) << 3;
    *(short8_t*)(&t[si][cj]) = *(const short8_t*)(v + (size_t)(s0 + si) * QLD + r0 + cj);
  }
  __syncthreads();
#pragma unroll
  for (int it = 0; it < 2; it++) {
    int f = it * 256 + tid;
    int ri = f >> 3, sj = (f & 7) << 3;
    short8_t o;
#pragma unroll
    for (int jj = 0; jj < 8; jj++) o[jj] = t[sj + jj][ri];
    *(short8_t*)(vT + (size_t)(r0 + ri) * SEQ + s0 + sj) = o;
  }
}

// ============================================================================
// GEMM-shaped flash attention, QBLK=128 (8 waves), in-register online softmax,
// 64-key chunks staged via global_load_lds with XOR col8 swizzle. Unchanged.
// ============================================================================
__global__ __launch_bounds__(512, 4) void attn_kernel(const unsigned short* __restrict__ qb,
                                                      const unsigned short* __restrict__ kb,
                                                      const unsigned short* __restrict__ vT,
                                                      unsigned short* __restrict__ attn_out) {
  const int h = blockIdx.x;
  const int qt = 15 - blockIdx.y;  // heavy qtiles dispatched first
  const int kvh = h >> 2;
  const int q0 = qt * 128;
  const int tid = threadIdx.x;
  const int w = tid >> 6, lane = tid & 63;
  const int quad = lane >> 4, l16 = lane & 15;
  const float SCALE = 0.08838834764831845f;  // 128^-0.5

  __shared__ unsigned short Ks[64 * 128];     // [key][d], XOR col8 swizzled
  __shared__ unsigned short VTs[128 * 64];    // [d][key], XOR col8 swizzled
  __shared__ unsigned short PTs[8 * 16 * 72]; // per-wave [q][key] stride 72

  unsigned short* pt = &PTs[w * 1152];

  const int krow = tid >> 4;                       // 0..31
  const int kc16 = tid & 15;
  const int kgcol = (kc16 ^ (krow & 7)) << 3;
  const unsigned short* kgbase = kb + (size_t)krow * QLD + kvh * 128 + kgcol;
  const int vrow = tid >> 3;                       // 0..63
  const int vc8 = tid & 7;
  const int vgcol = (vc8 ^ (vrow & 7)) << 3;
  const unsigned short* vgbase = vT + (size_t)(kvh * 128 + vrow) * 2048 + vgcol;
  unsigned short* ldsK = Ks + w * 512;
  unsigned short* ldsV = VTs + w * 512;

  bf16x8_t aq[4];
  {
    const unsigned short* qp = qb + (size_t)(q0 + w * 16 + l16) * QLD + h * 128 + quad * 8;
#pragma unroll
    for (int ks = 0; ks < 4; ks++)
      aq[ks] = __builtin_bit_cast(bf16x8_t, *(const short8_t*)(qp + ks * 32));
  }

  floatx4_t O[8] = {};
  float m_run[4], l_run[4];
#pragma unroll
  for (int r = 0; r < 4; r++) { m_run[r] = -3e38f; l_run[r] = 0.0f; }

  const int qmin = q0 + w * 16, qmax = qmin + 15;
  int kbeg = q0 - (WINDOW - 1); if (kbeg < 0) kbeg = 0;
  const int c0 = kbeg & ~63;
  const int nch = (q0 + 128 - c0) >> 6;
  const int sa = l16 & 7;

  for (int ci = 0; ci < nch; ci++) {
    const int kb0 = c0 + (ci << 6);
#pragma unroll
    for (int i = 0; i < 2; i++)
      load_lds16(kgbase + (size_t)(kb0 + i * 32) * QLD, ldsK + i * 4096);
#pragma unroll
    for (int i = 0; i < 2; i++)
      load_lds16(vgbase + kb0 + (size_t)(i * 64) * 2048, ldsV + i * 4096);
    __syncthreads();
    const bool alive = (kb0 <= qmax) && (kb0 + 63 >= qmin - (WINDOW - 1));
    if (alive) {
      floatx4_t S[4];
      __builtin_amdgcn_s_setprio(1);
#pragma unroll
      for (int j = 0; j < 4; j++) {
        floatx4_t acc = {};
        const int keyrow = j * 16 + l16;
#pragma unroll
        for (int ks = 0; ks < 4; ks++) {
          const int c16 = ((ks << 2) | quad) ^ sa;
          bf16x8_t bfk = __builtin_bit_cast(bf16x8_t,
              *(const short8_t*)(&Ks[keyrow * 128 + c16 * 8]));
          acc = __builtin_amdgcn_mfma_f32_16x16x32_bf16(aq[ks], bfk, acc, 0, 0, 0);
        }
        S[j] = acc;
      }
      __builtin_amdgcn_s_setprio(0);
      const bool need_mask = (kb0 + 63 > qmin) || (qmax - kb0 >= WINDOW);
      if (need_mask) {
#pragma unroll
        for (int j = 0; j < 4; j++) {
          const int key = kb0 + j * 16 + l16;
#pragma unroll
          for (int r = 0; r < 4; r++) {
            const int i = qmin + quad * 4 + r;
            const bool ok = (key <= i) && (i - key < WINDOW);
            S[j][r] = ok ? S[j][r] : -3e38f;
          }
        }
      }
      float mx[4], rs[4], alpha[4];
#pragma unroll
      for (int r = 0; r < 4; r++) {
        float m = S[0][r];
#pragma unroll
        for (int j = 1; j < 4; j++) m = fmaxf(m, S[j][r]);
#pragma unroll
        for (int d = 1; d < 16; d <<= 1) m = fmaxf(m, __shfl_xor(m, d, 16));
        mx[r] = fmaxf(m_run[r], m);
        alpha[r] = __expf(SCALE * (m_run[r] - mx[r]));
        m_run[r] = mx[r];
        rs[r] = 0.0f;
      }
#pragma unroll
      for (int j = 0; j < 4; j++) {
        float p[4];
#pragma unroll
        for (int r = 0; r < 4; r++) {
          const float sv = S[j][r];
          float e = __expf(SCALE * (sv - mx[r]));
          if (need_mask) e = (sv < -1e37f) ? 0.0f : e;
          p[r] = e;
          rs[r] += e;
        }
#pragma unroll
        for (int r = 0; r < 4; r++)
          pt[(quad * 4 + r) * 72 + j * 16 + l16] = (unsigned short)f2bf_bits(p[r]);
      }
#pragma unroll
      for (int r = 0; r < 4; r++) {
#pragma unroll
        for (int d = 1; d < 16; d <<= 1) rs[r] += __shfl_xor(rs[r], d, 16);
        l_run[r] = l_run[r] * alpha[r] + rs[r];
      }
#pragma unroll
      for (int nt = 0; nt < 8; nt++)
#pragma unroll
        for (int r = 0; r < 4; r++) O[nt][r] *= alpha[r];
      asm volatile("" ::: "memory");
      __builtin_amdgcn_s_setprio(1);
#pragma unroll
      for (int ks = 0; ks < 2; ks++) {
        bf16x8_t af = __builtin_bit_cast(bf16x8_t,
            *(const short8_t*)(&pt[l16 * 72 + ks * 32 + quad * 8]));
#pragma unroll
        for (int nt = 0; nt < 8; nt++) {
          const int c8 = (((ks << 2) | quad) ^ sa);
          bf16x8_t bfv = __builtin_bit_cast(bf16x8_t,
              *(const short8_t*)(&VTs[(nt * 16 + l16) * 64 + c8 * 8]));
          O[nt] = __builtin_amdgcn_mfma_f32_16x16x32_bf16(af, bfv, O[nt], 0, 0, 0);
        }
      }
      __builtin_amdgcn_s_setprio(0);
    }
    __syncthreads();
  }
  float inv_l[4];
#pragma unroll
  for (int r = 0; r < 4; r++) inv_l[r] = 1.0f / l_run[r];
#pragma unroll
  for (int nt = 0; nt < 8; nt++)
#pragma unroll
    for (int r = 0; r < 4; r++) {
      float v = O[nt][r] * inv_l[r];
      attn_out[(size_t)(qmin + quad * 4 + r) * 4096 + h * 128 + nt * 16 + l16] =
          (unsigned short)f2bf_bits(v);
    }
}

extern "C" void kernel_launch(void* const* d_in, const int* in_sizes, int n_in,
                              void* d_out, int out_size, void* d_ws, size_t ws_size,
                              hipStream_t stream) {
  (void)in_sizes; (void)n_in; (void)out_size; (void)ws_size;
  const float* x    = (const float*)d_in[0];
  const float* wq   = (const float*)d_in[1];
  const float* wk   = (const float*)d_in[2];
  const float* wv   = (const float*)d_in[3];
  const float* wo   = (const float*)d_in[4];
  const float* cosp = (const float*)d_in[5];
  const float* sinp = (const float*)d_in[6];
  float* out = (float*)d_out;
  char* ws = (char*)d_ws;

  // Region map (reuse; 92.3 MB total):
  //   wqkvb @0        (50.3MB, dead after QKV gemm)
  //       -> wob  @0        (33.6MB)
  //       -> vTb  @33.6MB   (4.2MB)
  //   xb    @50.3MB   (16.8MB, dead after QKV gemm)
  //       -> attnb @50.3MB  (16.8MB)
  //   qkvb  @67.1MB   (25.2MB: [2048][6144] bf16, rope applied in-gemm)
  unsigned short* wqkvb = (unsigned short*)(ws);
  unsigned short* wob   = (unsigned short*)(ws);
  unsigned short* vTb   = (unsigned short*)(ws + 33554432);
  unsigned short* xb    = (unsigned short*)(ws + 50331648);
  unsigned short* attnb = (unsigned short*)(ws + 50331648);
  unsigned short* qkvb  = (unsigned short*)(ws + 67108864);

  // 1: merged cvt of x, wq, wk, wv (wq rows 0-4095, wk 4096-5119, wv 5120-6143)
  cvt4_kernel<<<16384, 256, 0, stream>>>(
      x, wq, wk, wv,
      xb, wqkvb, wqkvb + (size_t)4096 * 4096, wqkvb + (size_t)5120 * 4096);
  // 2: fused QKV projection + RoPE, pipelined 256x192 tile -> 32x8 = 256
  //    blocks, 1/CU (84KB LDS), full fill
  gemm_pipe<unsigned short, true, 256, 192><<<dim3(32, 8), 512, 0, stream>>>(
      xb, wqkvb, qkvb, QLD, DIM, cosp, sinp, 5120);
  // 3: merged wo cvt (blocks 0-8191, wob overlays dead wqkvb) + v transpose
  epi_kernel<<<8704, 256, 0, stream>>>(wo, wob, qkvb + 5120, vTb);
  // 4: attention, QBLK=128 (q = qkvb, k = qkvb+4096, both ld QLD)
  attn_kernel<<<dim3(NH, 16), 512, 0, stream>>>(qkvb, qkvb + 4096, vTb, attnb);
  // 5: output projection, pipelined 128x256 tile -> 16x16 = 256 blocks, 1/CU
  gemm_pipe<float, false, 128, 256><<<dim3(16, 16), 512, 0, stream>>>(
      attnb, wob, out, 4096, DIM, nullptr, nullptr, 0);
}

// Round 5
// 467.457 us; speedup vs baseline: 1.0209x; 1.0209x over previous
//
#include <hip/hip_runtime.h>

#define DIM 4096
#define NH 32
#define NKV 8
#define HD 128
#define WINDOW 1024
#define SEQ 2048
#define QLD 6144  // fused QKV row stride (u16 elems)

typedef unsigned int uint32;
typedef __attribute__((ext_vector_type(8))) short short8_t;
typedef __attribute__((ext_vector_type(8))) __bf16 bf16x8_t;
typedef __attribute__((ext_vector_type(4))) float floatx4_t;

__device__ __forceinline__ uint32 f2bf_bits(float f) {
  uint32 u = __builtin_bit_cast(uint32, f);
  return (u + 0x7fffu + ((u >> 16) & 1u)) >> 16;
}
__device__ __forceinline__ float bf2f(unsigned short b) {
  return __builtin_bit_cast(float, ((uint32)b) << 16);
}

template <class X, class Y> struct same_t { static constexpr bool v = false; };
template <class X> struct same_t<X, X> { static constexpr bool v = true; };

__device__ __forceinline__ void load_lds16(const unsigned short* g, unsigned short* l) {
  __builtin_amdgcn_global_load_lds((__attribute__((address_space(1))) void*)g,
                                   (__attribute__((address_space(3))) void*)l, 16, 0, 0);
}

// ============================================================================
// Counted-vmcnt bf16 GEMM v2: C[M,N] = A[M,K]*B[N,K]^T. BK=64, 2 LDS buffers,
// 8 waves (2M x 4N, 512 thr). Loop: vmcnt(IT) [tile t retired, t+1 in flight]
// -> barrier -> reads+MFMA (one compiler-scheduled block, fine lgkmcnt
// interleave) -> lgkmcnt(0)+barrier [all reads retired] -> stage(t+2) into
// the just-read buffer. 2 barriers per 2*MI*NJ MFMA/wave; vmcnt NEVER drains
// in-loop (the m97 ~20% stall); stage never targets a buffer being read.
// XOR col8 swizzle (session-verified, 0 bank conflicts): LDS[row][slot] holds
// global chunk slot^(row&7); applied by pre-swizzled per-lane global source
// (linear gload_lds dest), read back with the same XOR.
// Grids sized to exactly 256 blocks at 1 block/CU (LDS > 80KB): full fill.
// ROPE=true: rotary fused into epilogue for cols < rope_ncols.
// ============================================================================
template <typename TC, bool ROPE, int BM, int BN>
__global__ __launch_bounds__(512, 2) void gemm_pipe2(const unsigned short* __restrict__ A,
                                                     const unsigned short* __restrict__ B,
                                                     TC* __restrict__ C, int N, int K,
                                                     const float* __restrict__ cosp,
                                                     const float* __restrict__ sinp,
                                                     int rope_ncols) {
  constexpr int BK = 64;
  constexpr int MI = BM / 32;   // A frags per wave per ks
  constexpr int NJ = BN / 64;   // B frags per wave per ks
  constexpr int IA = BM / 64;   // A staging issues per K-tile (64 rows each)
  constexpr int IB = BN / 64;
  constexpr int IT = IA + IB;
  constexpr int AE = BM * BK;   // A-tile elems per buffer
  constexpr int BUFE = (BM + BN) * BK;
  __shared__ unsigned short lds[2 * BUFE];

  const int tid = threadIdx.x;
  const int w = tid >> 6, lane = tid & 63;
  const int quad = lane >> 4, l16 = lane & 15;
  const int wm = w >> 2, wn = w & 3;
  const size_t m0 = (size_t)blockIdx.y * BM, n0 = (size_t)blockIdx.x * BN;

  // staging: one issue = 64 rows x 128B; thread -> row tid>>3, slot tid&7;
  // pre-swizzled source chunk = slot ^ (row&7)
  const int srow = tid >> 3;
  const int schunk = ((tid & 7) ^ (srow & 7)) << 3;
  const unsigned short* asrc[IA];
  const unsigned short* bsrc[IB];
#pragma unroll
  for (int ii = 0; ii < IA; ii++)
    asrc[ii] = A + (m0 + ii * 64 + srow) * (size_t)K + schunk;
#pragma unroll
  for (int ii = 0; ii < IB; ii++)
    bsrc[ii] = B + (n0 + ii * 64 + srow) * (size_t)K + schunk;
  const int w512 = w * 512;

  auto stage = [&](int kt, int bsel) {
    unsigned short* buf = lds + bsel * BUFE;
    const size_t ko = (size_t)kt * BK;
#pragma unroll
    for (int ii = 0; ii < IA; ii++)
      load_lds16(asrc[ii] + ko, buf + ii * 4096 + w512);
#pragma unroll
    for (int ii = 0; ii < IB; ii++)
      load_lds16(bsrc[ii] + ko, buf + AE + ii * 4096 + w512);
  };

  floatx4_t acc[MI][NJ] = {};
  const int sa = l16 & 7;
  const int nt = K >> 6;

  stage(0, 0);
  stage(1, 1);

  for (int t = 0; t < nt; t++) {
    // tile t's IT issues retired (own wave); tile t+1's stay in flight
    if (t + 1 < nt) {
      if constexpr (IT == 7) asm volatile("s_waitcnt vmcnt(7)" ::: "memory");
      else                   asm volatile("s_waitcnt vmcnt(6)" ::: "memory");
    } else {
      asm volatile("s_waitcnt vmcnt(0)" ::: "memory");
    }
    __builtin_amdgcn_s_barrier();      // all waves' tile-t loads retired
    asm volatile("" ::: "memory");     // pin ds_reads below the barrier
    const unsigned short* buf = lds + (t & 1) * BUFE;
#pragma unroll
    for (int ks = 0; ks < 2; ks++) {
      bf16x8_t afr[MI], bfr[NJ];
      const int cs = (((ks << 2) | quad) ^ sa) << 3;
#pragma unroll
      for (int i = 0; i < MI; i++) {
        const int row = wm * (BM / 2) + i * 16 + l16;
        afr[i] = __builtin_bit_cast(bf16x8_t, *(const short8_t*)(buf + row * 64 + cs));
      }
#pragma unroll
      for (int j = 0; j < NJ; j++) {
        const int row = wn * (BN / 4) + j * 16 + l16;
        bfr[j] = __builtin_bit_cast(bf16x8_t, *(const short8_t*)(buf + AE + row * 64 + cs));
      }
#pragma unroll
      for (int i = 0; i < MI; i++)
#pragma unroll
        for (int j = 0; j < NJ; j++)
          acc[i][j] = __builtin_amdgcn_mfma_f32_16x16x32_bf16(afr[i], bfr[j], acc[i][j], 0, 0, 0);
    }
    asm volatile("s_waitcnt lgkmcnt(0)" ::: "memory");  // own reads retired
    __builtin_amdgcn_s_barrier();      // all waves' reads of this buf retired
    asm volatile("" ::: "memory");     // pin stage below the barrier
    if (t + 2 < nt) stage(t + 2, t & 1);
  }

  // --- epilogue (+ optional fused RoPE) ---
#pragma unroll
  for (int i = 0; i < MI; i++)
#pragma unroll
    for (int j = 0; j < NJ; j++) {
      const int colb = (int)n0 + wn * (BN / 4) + j * 16;  // wave-uniform
      const bool do_rope = ROPE && (colb < rope_ncols);
#pragma unroll
      for (int r = 0; r < 4; r++) {
        size_t row = m0 + wm * (BM / 2) + i * 16 + quad * 4 + r;
        size_t col = n0 + wn * (BN / 4) + j * 16 + l16;
        float v = acc[i][j][r];
        if constexpr (ROPE) {
          if (do_rope) {  // 16-col tile never straddles rope_ncols (mult of 16)
            float pv = __shfl_xor(v, 1);
            const int d = ((int)col & 127) >> 1;
            const float c = cosp[row * 64 + d];
            const float s = sinp[row * 64 + d];
            v = ((int)col & 1) ? (pv * s + v * c) : (v * c - pv * s);
          }
        }
        if constexpr (same_t<TC, float>::v)
          C[row * (size_t)N + col] = v;
        else
          C[row * (size_t)N + col] = (unsigned short)f2bf_bits(v);
      }
    }
}

// Merged fp32->bf16 convert for {x, wq, wk, wv}: region-dispatched by block.
__global__ __launch_bounds__(256) void cvt4_kernel(const float* __restrict__ s0,
                                                   const float* __restrict__ s1,
                                                   const float* __restrict__ s2,
                                                   const float* __restrict__ s3,
                                                   unsigned short* __restrict__ d0,
                                                   unsigned short* __restrict__ d1,
                                                   unsigned short* __restrict__ d2,
                                                   unsigned short* __restrict__ d3) {
  const int b = blockIdx.x;
  const float* src;
  unsigned short* dst;
  int rb;
  if (b < 4096)        { src = s0; dst = d0; rb = b; }
  else if (b < 12288)  { src = s1; dst = d1; rb = b - 4096; }
  else if (b < 14336)  { src = s2; dst = d2; rb = b - 12288; }
  else                 { src = s3; dst = d3; rb = b - 14336; }
  const int idx = rb * 256 + threadIdx.x;
  const float4* p = (const float4*)src + (size_t)idx * 2;
  float4 a = p[0], bb = p[1];
  uint32 w0 = f2bf_bits(a.x) | (f2bf_bits(a.y) << 16);
  uint32 w1 = f2bf_bits(a.z) | (f2bf_bits(a.w) << 16);
  uint32 w2 = f2bf_bits(bb.x) | (f2bf_bits(bb.y) << 16);
  uint32 w3 = f2bf_bits(bb.z) | (f2bf_bits(bb.w) << 16);
  ((uint4*)dst)[idx] = make_uint4(w0, w1, w2, w3);
}

// Merged post-QKV-GEMM launch: blocks [0,8192) convert wo fp32->bf16 into wob;
// blocks [8192,8704) transpose v (qkvb col 5120, ld QLD) into vT[r][s].
__global__ __launch_bounds__(256) void epi_kernel(const float* __restrict__ wo,
                                                  unsigned short* __restrict__ wob,
                                                  const unsigned short* __restrict__ v,
                                                  unsigned short* __restrict__ vT) {
  __shared__ unsigned short t[64][72];
  const int b = blockIdx.x;
  const int tid = threadIdx.x;
  if (b < 8192) {
    const int idx = b * 256 + tid;
    const float4* p = (const float4*)wo + (size_t)idx * 2;
    float4 a = p[0], bb = p[1];
    uint32 w0 = f2bf_bits(a.x) | (f2bf_bits(a.y) << 16);
    uint32 w1 = f2bf_bits(a.z) | (f2bf_bits(a.w) << 16);
    uint32 w2 = f2bf_bits(bb.x) | (f2bf_bits(bb.y) << 16);
    uint32 w3 = f2bf_bits(bb.z) | (f2bf_bits(bb.w) << 16);
    ((uint4*)wob)[idx] = make_uint4(w0, w1, w2, w3);
    return;
  }
  const int bx = b - 8192;
  const int r0 = (bx & 15) * 64, s0 = (bx >> 4) * 64;
#pragma unroll
  for (int it = 0; it < 2; it++) {
    int f = it * 256 + tid;
    int si = f >> 3, cj = (f & 7) << 3;
    *(short8_t*)(&t[si][cj]) = *(const short8_t*)(v + (size_t)(s0 + si) * QLD + r0 + cj);
  }
  __syncthreads();
#pragma unroll
  for (int it = 0; it < 2; it++) {
    int f = it * 256 + tid;
    int ri = f >> 3, sj = (f & 7) << 3;
    short8_t o;
#pragma unroll
    for (int jj = 0; jj < 8; jj++) o[jj] = t[sj + jj][ri];
    *(short8_t*)(vT + (size_t)(r0 + ri) * SEQ + s0 + sj) = o;
  }
}

// ============================================================================
// GEMM-shaped flash attention, QBLK=128 (8 waves), in-register online softmax,
// 64-key chunks staged via global_load_lds with XOR col8 swizzle. Unchanged.
// ============================================================================
__global__ __launch_bounds__(512, 4) void attn_kernel(const unsigned short* __restrict__ qb,
                                                      const unsigned short* __restrict__ kb,
                                                      const unsigned short* __restrict__ vT,
                                                      unsigned short* __restrict__ attn_out) {
  const int h = blockIdx.x;
  const int qt = 15 - blockIdx.y;  // heavy qtiles dispatched first
  const int kvh = h >> 2;
  const int q0 = qt * 128;
  const int tid = threadIdx.x;
  const int w = tid >> 6, lane = tid & 63;
  const int quad = lane >> 4, l16 = lane & 15;
  const float SCALE = 0.08838834764831845f;  // 128^-0.5

  __shared__ unsigned short Ks[64 * 128];     // [key][d], XOR col8 swizzled
  __shared__ unsigned short VTs[128 * 64];    // [d][key], XOR col8 swizzled
  __shared__ unsigned short PTs[8 * 16 * 72]; // per-wave [q][key] stride 72

  unsigned short* pt = &PTs[w * 1152];

  const int krow = tid >> 4;                       // 0..31
  const int kc16 = tid & 15;
  const int kgcol = (kc16 ^ (krow & 7)) << 3;
  const unsigned short* kgbase = kb + (size_t)krow * QLD + kvh * 128 + kgcol;
  const int vrow = tid >> 3;                       // 0..63
  const int vc8 = tid & 7;
  const int vgcol = (vc8 ^ (vrow & 7)) << 3;
  const unsigned short* vgbase = vT + (size_t)(kvh * 128 + vrow) * 2048 + vgcol;
  unsigned short* ldsK = Ks + w * 512;
  unsigned short* ldsV = VTs + w * 512;

  bf16x8_t aq[4];
  {
    const unsigned short* qp = qb + (size_t)(q0 + w * 16 + l16) * QLD + h * 128 + quad * 8;
#pragma unroll
    for (int ks = 0; ks < 4; ks++)
      aq[ks] = __builtin_bit_cast(bf16x8_t, *(const short8_t*)(qp + ks * 32));
  }

  floatx4_t O[8] = {};
  float m_run[4], l_run[4];
#pragma unroll
  for (int r = 0; r < 4; r++) { m_run[r] = -3e38f; l_run[r] = 0.0f; }

  const int qmin = q0 + w * 16, qmax = qmin + 15;
  int kbeg = q0 - (WINDOW - 1); if (kbeg < 0) kbeg = 0;
  const int c0 = kbeg & ~63;
  const int nch = (q0 + 128 - c0) >> 6;
  const int sa = l16 & 7;

  for (int ci = 0; ci < nch; ci++) {
    const int kb0 = c0 + (ci << 6);
#pragma unroll
    for (int i = 0; i < 2; i++)
      load_lds16(kgbase + (size_t)(kb0 + i * 32) * QLD, ldsK + i * 4096);
#pragma unroll
    for (int i = 0; i < 2; i++)
      load_lds16(vgbase + kb0 + (size_t)(i * 64) * 2048, ldsV + i * 4096);
    __syncthreads();
    const bool alive = (kb0 <= qmax) && (kb0 + 63 >= qmin - (WINDOW - 1));
    if (alive) {
      floatx4_t S[4];
      __builtin_amdgcn_s_setprio(1);
#pragma unroll
      for (int j = 0; j < 4; j++) {
        floatx4_t acc = {};
        const int keyrow = j * 16 + l16;
#pragma unroll
        for (int ks = 0; ks < 4; ks++) {
          const int c16 = ((ks << 2) | quad) ^ sa;
          bf16x8_t bfk = __builtin_bit_cast(bf16x8_t,
              *(const short8_t*)(&Ks[keyrow * 128 + c16 * 8]));
          acc = __builtin_amdgcn_mfma_f32_16x16x32_bf16(aq[ks], bfk, acc, 0, 0, 0);
        }
        S[j] = acc;
      }
      __builtin_amdgcn_s_setprio(0);
      const bool need_mask = (kb0 + 63 > qmin) || (qmax - kb0 >= WINDOW);
      if (need_mask) {
#pragma unroll
        for (int j = 0; j < 4; j++) {
          const int key = kb0 + j * 16 + l16;
#pragma unroll
          for (int r = 0; r < 4; r++) {
            const int i = qmin + quad * 4 + r;
            const bool ok = (key <= i) && (i - key < WINDOW);
            S[j][r] = ok ? S[j][r] : -3e38f;
          }
        }
      }
      float mx[4], rs[4], alpha[4];
#pragma unroll
      for (int r = 0; r < 4; r++) {
        float m = S[0][r];
#pragma unroll
        for (int j = 1; j < 4; j++) m = fmaxf(m, S[j][r]);
#pragma unroll
        for (int d = 1; d < 16; d <<= 1) m = fmaxf(m, __shfl_xor(m, d, 16));
        mx[r] = fmaxf(m_run[r], m);
        alpha[r] = __expf(SCALE * (m_run[r] - mx[r]));
        m_run[r] = mx[r];
        rs[r] = 0.0f;
      }
#pragma unroll
      for (int j = 0; j < 4; j++) {
        float p[4];
#pragma unroll
        for (int r = 0; r < 4; r++) {
          const float sv = S[j][r];
          float e = __expf(SCALE * (sv - mx[r]));
          if (need_mask) e = (sv < -1e37f) ? 0.0f : e;
          p[r] = e;
          rs[r] += e;
        }
#pragma unroll
        for (int r = 0; r < 4; r++)
          pt[(quad * 4 + r) * 72 + j * 16 + l16] = (unsigned short)f2bf_bits(p[r]);
      }
#pragma unroll
      for (int r = 0; r < 4; r++) {
#pragma unroll
        for (int d = 1; d < 16; d <<= 1) rs[r] += __shfl_xor(rs[r], d, 16);
        l_run[r] = l_run[r] * alpha[r] + rs[r];
      }
#pragma unroll
      for (int nt = 0; nt < 8; nt++)
#pragma unroll
        for (int r = 0; r < 4; r++) O[nt][r] *= alpha[r];
      asm volatile("" ::: "memory");
      __builtin_amdgcn_s_setprio(1);
#pragma unroll
      for (int ks = 0; ks < 2; ks++) {
        bf16x8_t af = __builtin_bit_cast(bf16x8_t,
            *(const short8_t*)(&pt[l16 * 72 + ks * 32 + quad * 8]));
#pragma unroll
        for (int nt = 0; nt < 8; nt++) {
          const int c8 = (((ks << 2) | quad) ^ sa);
          bf16x8_t bfv = __builtin_bit_cast(bf16x8_t,
              *(const short8_t*)(&VTs[(nt * 16 + l16) * 64 + c8 * 8]));
          O[nt] = __builtin_amdgcn_mfma_f32_16x16x32_bf16(af, bfv, O[nt], 0, 0, 0);
        }
      }
      __builtin_amdgcn_s_setprio(0);
    }
    __syncthreads();
  }
  float inv_l[4];
#pragma unroll
  for (int r = 0; r < 4; r++) inv_l[r] = 1.0f / l_run[r];
#pragma unroll
  for (int nt = 0; nt < 8; nt++)
#pragma unroll
    for (int r = 0; r < 4; r++) {
      float v = O[nt][r] * inv_l[r];
      attn_out[(size_t)(qmin + quad * 4 + r) * 4096 + h * 128 + nt * 16 + l16] =
          (unsigned short)f2bf_bits(v);
    }
}

extern "C" void kernel_launch(void* const* d_in, const int* in_sizes, int n_in,
                              void* d_out, int out_size, void* d_ws, size_t ws_size,
                              hipStream_t stream) {
  (void)in_sizes; (void)n_in; (void)out_size; (void)ws_size;
  const float* x    = (const float*)d_in[0];
  const float* wq   = (const float*)d_in[1];
  const float* wk   = (const float*)d_in[2];
  const float* wv   = (const float*)d_in[3];
  const float* wo   = (const float*)d_in[4];
  const float* cosp = (const float*)d_in[5];
  const float* sinp = (const float*)d_in[6];
  float* out = (float*)d_out;
  char* ws = (char*)d_ws;

  // Region map (reuse; 92.3 MB total):
  //   wqkvb @0        (50.3MB, dead after QKV gemm)
  //       -> wob  @0        (33.6MB)
  //       -> vTb  @33.6MB   (4.2MB)
  //   xb    @50.3MB   (16.8MB, dead after QKV gemm)
  //       -> attnb @50.3MB  (16.8MB)
  //   qkvb  @67.1MB   (25.2MB: [2048][6144] bf16, rope applied in-gemm)
  unsigned short* wqkvb = (unsigned short*)(ws);
  unsigned short* wob   = (unsigned short*)(ws);
  unsigned short* vTb   = (unsigned short*)(ws + 33554432);
  unsigned short* xb    = (unsigned short*)(ws + 50331648);
  unsigned short* attnb = (unsigned short*)(ws + 50331648);
  unsigned short* qkvb  = (unsigned short*)(ws + 67108864);

  // 1: merged cvt of x, wq, wk, wv (wq rows 0-4095, wk 4096-5119, wv 5120-6143)
  cvt4_kernel<<<16384, 256, 0, stream>>>(
      x, wq, wk, wv,
      xb, wqkvb, wqkvb + (size_t)4096 * 4096, wqkvb + (size_t)5120 * 4096);
  // 2: fused QKV projection + RoPE, counted-vmcnt 256x192 tile -> 32x8 = 256
  //    blocks, 1/CU (112KB LDS), full fill
  gemm_pipe2<unsigned short, true, 256, 192><<<dim3(32, 8), 512, 0, stream>>>(
      xb, wqkvb, qkvb, QLD, DIM, cosp, sinp, 5120);
  // 3: merged wo cvt (blocks 0-8191, wob overlays dead wqkvb) + v transpose
  epi_kernel<<<8704, 256, 0, stream>>>(wo, wob, qkvb + 5120, vTb);
  // 4: attention, QBLK=128 (q = qkvb, k = qkvb+4096, both ld QLD)
  attn_kernel<<<dim3(NH, 16), 512, 0, stream>>>(qkvb, qkvb + 4096, vTb, attnb);
  // 5: output projection, counted-vmcnt 128x256 tile -> 16x16 = 256 blocks, 1/CU
  gemm_pipe2<float, false, 128, 256><<<dim3(16, 16), 512, 0, stream>>>(
      attnb, wob, out, 4096, DIM, nullptr, nullptr, 0);
}